// Round 2
// baseline (181.656 us; speedup 1.0000x reference)
//
#include <hip/hip_runtime.h>
#include <hip/hip_fp8.h>
#include <hip/hip_fp16.h>

// SumLayer: weighted logsumexp over E children per node.
// N=32768, E=32, B=256, MAX_ELS=65536.
//
// R5 design. History:
//  R0-R2: fetch-bound, 3.7 TB/s L2-miss. R3: fp8 G table (16MB). R4: chunk-major
//  G[chunk][row][32B] + blockIdx%8 XCD slicing + packed u32 WC (u16 cid | f16 w):
//  sum_main FETCH 337MB -> 25.1MB (compulsory), but dur stuck at 44us, 1.3TB/s,
//  VALUBusy 41%, VGPR=32 -> now ISSUE/LATENCY-bound, not fetch-bound.
// R5 levers (traffic unchanged, instructions/latency attacked):
//  1) 4 lanes/node x dwordx2 gathers (was 8 x dword): halves gather instrs and
//     per-gather ds_read/unpack/addr overhead; 8 f32 accs/lane.
//  2) explicit double-buffered load groups of 8 (static A/B reg arrays):
//     ~16 gathers in flight/wave; L2 latency hides under compute group.
//  3) exp_convert remapped: wave = (32 rows x 1 chunk) -> reads 32 full 128B
//     lines, writes 1024B contiguous (R4 had 2MB-strided 16B scatter stores).
// Predicted: sum_main 44 -> ~25us, exp_convert ~14us, total ~135-155us.

constexpr int NN = 32768;
constexpr int EE = 32;
constexpr int BB = 256;
constexpr int MAX_ELS = 65536;

constexpr int NCHUNK = 8;                 // column chunks == XCD count
constexpr int CHUNK_COLS = 32;            // fp8 bytes per row per chunk
constexpr size_t SLICE_BYTES = (size_t)MAX_ELS * CHUNK_COLS;  // 2 MB
constexpr int NPB = 64;                   // nodes per block (main kernel)

typedef float floatx2 __attribute__((ext_vector_type(2)));

__device__ inline int pack4_fp8(float4 v) {
    const int a = __hip_cvt_float_to_fp8(__expf(v.x), __HIP_SATFINITE, __HIP_E4M3);
    const int b = __hip_cvt_float_to_fp8(__expf(v.y), __HIP_SATFINITE, __HIP_E4M3);
    const int c = __hip_cvt_float_to_fp8(__expf(v.z), __HIP_SATFINITE, __HIP_E4M3);
    const int d = __hip_cvt_float_to_fp8(__expf(v.w), __HIP_SATFINITE, __HIP_E4M3);
    return a | (b << 8) | (c << 16) | (d << 24);
}

// ---- pre-pass 1: G[c][r][0..31] = fp8(exp(element_mars[r][c*32..c*32+31])) ----
// wave -> (32-row group, one chunk). lane l: r_local = l>>1, half h = l&1.
// read: em[r][c*32+h*16 .. +16) = 64B (em line 128B == one (row,chunk) slice).
// write: G + c*2MB + r*32 + h*16 -> per-wave 1024B fully contiguous.
__global__ __launch_bounds__(256)
void exp_convert_kernel(const float4* __restrict__ em, unsigned char* __restrict__ G)
{
    const int wid  = blockIdx.x * 4 + (threadIdx.x >> 6);
    const int lane = threadIdx.x & 63;
    const int c    = wid & 7;
    const int rg   = wid >> 3;                  // [0, 2048)
    const int r    = rg * 32 + (lane >> 1);
    const int h    = lane & 1;

    const float4* src = em + (size_t)r * 64 + c * 8 + h * 4;
    const float4 v0 = src[0], v1 = src[1], v2 = src[2], v3 = src[3];
    int4 o;
    o.x = pack4_fp8(v0);
    o.y = pack4_fp8(v1);
    o.z = pack4_fp8(v2);
    o.w = pack4_fp8(v3);
    *reinterpret_cast<int4*>(G + (size_t)c * SLICE_BYTES + (size_t)r * CHUNK_COLS
                               + h * 16) = o;
}

// ---- pre-pass 2: WC[i] = (cids[i] as u16) | (f16(params[pids[i]]) << 16) ----
__global__ __launch_bounds__(256)
void pack_wc_kernel(const float* __restrict__ params, const int* __restrict__ cids,
                    const int* __restrict__ pids, unsigned int* __restrict__ WC)
{
    const int i = blockIdx.x * 256 + threadIdx.x;
    const unsigned int cid = (unsigned int)cids[i] & 0xFFFFu;   // MAX_ELS = 2^16
    const float w = params[pids[i]];
    const unsigned int h = (unsigned int)__half_as_ushort(__float2half(w));
    WC[i] = cid | (h << 16);
}

// ---- main: 64 nodes/block x 32 cols; chunk = blockIdx%8 -> XCD L2 slice ----
// 16 nodes/wave, 4 lanes/node, dwordx2 (8 fp8 cols) per gather.
__global__ __launch_bounds__(256)
void sum_main_kernel(const unsigned char* __restrict__ G, const unsigned int* __restrict__ WC,
                     const int* __restrict__ nids, float* __restrict__ out)
{
    const int chunk = blockIdx.x & (NCHUNK - 1);
    const int g     = blockIdx.x >> 3;          // node-group of 64
    const int tid   = threadIdx.x;

    // packed (cid,w); stride 33 -> e-indexed reads land on distinct banks.
    __shared__ unsigned int s_wc[NPB * 33];
    {
        const int4* WC4 = reinterpret_cast<const int4*>(WC);
        const int4 v0 = WC4[g * 512 + tid];
        const int4 v1 = WC4[g * 512 + 256 + tid];
        const int n0 = tid >> 3;
        const int e0 = (tid & 7) * 4;
        s_wc[n0 * 33 + e0 + 0] = (unsigned int)v0.x;
        s_wc[n0 * 33 + e0 + 1] = (unsigned int)v0.y;
        s_wc[n0 * 33 + e0 + 2] = (unsigned int)v0.z;
        s_wc[n0 * 33 + e0 + 3] = (unsigned int)v0.w;
        const int n1 = 32 + n0;
        s_wc[n1 * 33 + e0 + 0] = (unsigned int)v1.x;
        s_wc[n1 * 33 + e0 + 1] = (unsigned int)v1.y;
        s_wc[n1 * 33 + e0 + 2] = (unsigned int)v1.z;
        s_wc[n1 * 33 + e0 + 3] = (unsigned int)v1.w;
    }
    __syncthreads();

    const int wave = tid >> 6;
    const int lane = tid & 63;
    const int nl   = wave * 16 + (lane >> 2);   // node-local 0..63
    const int l4   = lane & 3;                  // 8 cols of the 32-col slice
    const unsigned char* Gs = G + (size_t)chunk * SLICE_BYTES + l4 * 8;
    const unsigned int* wcrow = s_wc + nl * 33;

    float acc[8] = {0.f, 0.f, 0.f, 0.f, 0.f, 0.f, 0.f, 0.f};
    unsigned int wcA[8], wcB[8];
    uint2 uA[8], uB[8];

#define LOAD_GRP(WCB, UB, EO)                                                   \
    _Pragma("unroll")                                                           \
    for (int j = 0; j < 8; ++j) {                                               \
        const unsigned int wc = wcrow[(EO) + j];                                \
        WCB[j] = wc;                                                            \
        UB[j] = *reinterpret_cast<const uint2*>(Gs + ((wc & 0xFFFFu) << 5));    \
    }

#define COMP_GRP(WCB, UB)                                                       \
    _Pragma("unroll")                                                           \
    for (int j = 0; j < 8; ++j) {                                               \
        const float w = __half2float(__ushort_as_half(                          \
            (unsigned short)(WCB[j] >> 16)));                                   \
        const floatx2 l0 = __builtin_amdgcn_cvt_pk_f32_fp8(UB[j].x, false);     \
        const floatx2 h0 = __builtin_amdgcn_cvt_pk_f32_fp8(UB[j].x, true);      \
        const floatx2 l1 = __builtin_amdgcn_cvt_pk_f32_fp8(UB[j].y, false);     \
        const floatx2 h1 = __builtin_amdgcn_cvt_pk_f32_fp8(UB[j].y, true);      \
        acc[0] = fmaf(l0.x, w, acc[0]);                                         \
        acc[1] = fmaf(l0.y, w, acc[1]);                                         \
        acc[2] = fmaf(h0.x, w, acc[2]);                                         \
        acc[3] = fmaf(h0.y, w, acc[3]);                                         \
        acc[4] = fmaf(l1.x, w, acc[4]);                                         \
        acc[5] = fmaf(l1.y, w, acc[5]);                                         \
        acc[6] = fmaf(h1.x, w, acc[6]);                                         \
        acc[7] = fmaf(h1.y, w, acc[7]);                                         \
    }

    LOAD_GRP(wcA, uA, 0);
    LOAD_GRP(wcB, uB, 8);       // ~16 gathers in flight
    COMP_GRP(wcA, uA);
    LOAD_GRP(wcA, uA, 16);
    COMP_GRP(wcB, uB);
    LOAD_GRP(wcB, uB, 24);
    COMP_GRP(wcA, uA);
    COMP_GRP(wcB, uB);
#undef LOAD_GRP
#undef COMP_GRP

    float4 r0, r1;
    r0.x = __logf(fmaxf(acc[0], 1e-10f));
    r0.y = __logf(fmaxf(acc[1], 1e-10f));
    r0.z = __logf(fmaxf(acc[2], 1e-10f));
    r0.w = __logf(fmaxf(acc[3], 1e-10f));
    r1.x = __logf(fmaxf(acc[4], 1e-10f));
    r1.y = __logf(fmaxf(acc[5], 1e-10f));
    r1.z = __logf(fmaxf(acc[6], 1e-10f));
    r1.w = __logf(fmaxf(acc[7], 1e-10f));

    const int n   = g * NPB + nl;
    const int row = nids[n];
    float* op = out + (size_t)row * BB + chunk * CHUNK_COLS + l4 * 8;
    *reinterpret_cast<float4*>(op)     = r0;
    *reinterpret_cast<float4*>(op + 4) = r1;
}

// ---- fallback (ws too small): standalone fp32 version ----
__global__ __launch_bounds__(256, 2)
void sum_layer_fallback(const float* __restrict__ element_mars,
                        const float* __restrict__ params,
                        const int* __restrict__ nids,
                        const int* __restrict__ cids,
                        const int* __restrict__ pids,
                        float* __restrict__ out)
{
    const int tid  = threadIdx.x;
    const int wave = tid >> 6;
    const int lane = tid & 63;

    __shared__ int   s_cid[4][EE];
    __shared__ float s_w[4][EE];
    if (tid < 4 * EE) {
        const int wi = tid >> 5, e = tid & (EE - 1);
        const int gn = blockIdx.x * 4 + wi;
        s_cid[wi][e] = cids[gn * EE + e];
        s_w[wi][e]   = params[pids[gn * EE + e]];
    }
    __syncthreads();

    const int n = blockIdx.x * 4 + wave;
    float4 acc = make_float4(0.f, 0.f, 0.f, 0.f);
#pragma unroll
    for (int e = 0; e < EE; ++e) {
        const float4 v = *reinterpret_cast<const float4*>(
            element_mars + (size_t)s_cid[wave][e] * BB + 4 * lane);
        const float w = s_w[wave][e];
        acc.x = fmaf(__expf(v.x), w, acc.x);
        acc.y = fmaf(__expf(v.y), w, acc.y);
        acc.z = fmaf(__expf(v.z), w, acc.z);
        acc.w = fmaf(__expf(v.w), w, acc.w);
    }
    float4 r;
    r.x = __logf(fmaxf(acc.x, 1e-10f));
    r.y = __logf(fmaxf(acc.y, 1e-10f));
    r.z = __logf(fmaxf(acc.z, 1e-10f));
    r.w = __logf(fmaxf(acc.w, 1e-10f));
    *reinterpret_cast<float4*>(out + (size_t)nids[n] * BB + 4 * lane) = r;
}

extern "C" void kernel_launch(void* const* d_in, const int* in_sizes, int n_in,
                              void* d_out, int out_size, void* d_ws, size_t ws_size,
                              hipStream_t stream) {
    // inputs: node_mars[N,B], element_mars[MAX_ELS,B], params[N*E],
    //         nids[N], cids[N,E], pids[N,E]
    const float* element_mars = (const float*)d_in[1];
    const float* params       = (const float*)d_in[2];
    const int*   nids         = (const int*)d_in[3];
    const int*   cids         = (const int*)d_in[4];
    const int*   pids         = (const int*)d_in[5];
    float*       out          = (float*)d_out;

    const size_t g_bytes  = (size_t)NCHUNK * SLICE_BYTES;           // 16MB fp8
    const size_t wc_bytes = (size_t)NN * EE * sizeof(unsigned int); // 4MB

    if (ws_size >= g_bytes + wc_bytes) {
        unsigned char* G  = (unsigned char*)d_ws;
        unsigned int*  WC = (unsigned int*)((char*)d_ws + g_bytes);

        exp_convert_kernel<<<(MAX_ELS / 32) * NCHUNK / 4, 256, 0, stream>>>(
            (const float4*)element_mars, G);
        pack_wc_kernel<<<(NN * EE) / 256, 256, 0, stream>>>(params, cids, pids, WC);
        sum_main_kernel<<<(NN / NPB) * NCHUNK, 256, 0, stream>>>(G, WC, nids, out);
    } else {
        sum_layer_fallback<<<NN / 4, 256, 0, stream>>>(
            element_mars, params, nids, cids, pids, out);
    }
}

// Round 3
// 174.922 us; speedup vs baseline: 1.0385x; 1.0385x over previous
//
#include <hip/hip_runtime.h>
#include <hip/hip_fp8.h>
#include <hip/hip_fp16.h>

// SumLayer: weighted logsumexp over E children per node.
// N=32768, E=32, B=256, MAX_ELS=65536.
//
// R6 design. History:
//  R0-R2: fetch-bound (3.7 TB/s L2-miss). R3: fp8 G (16MB). R4: chunk-major
//  G[chunk][row][32B], blockIdx%8 XCD slicing, WC = u16 cid | f16 w ->
//  FETCH 337->25MB but dur stuck ~44-46us @ <50% on every counter.
//  R4 vs R5 invariant: time tracks the COUNT of random 32B L2 requests
//  (8.4M = N*E*8chunks), not instructions, not in-flight depth, not fetch.
//  => L2 small-random-request throughput ceiling (~9.4 req/cyc/XCD).
// R6 lever: same logical bytes, HALF the requests. CHUNK_COLS 32->64:
//  one aligned 64B request per (node,e) gather (4 lanes x dwordx4).
//  NCHUNK=4 -> slice 4MB, resident on 2 XCDs (blockIdx%8 in {c,c+4}).
//  WC loads + out stores nontemporal so streams don't evict the G slice.
// Predicted: sum_main 46.5 -> 24-30us, FETCH 25->~40MB; total ~158-165us.

constexpr int NN = 32768;
constexpr int EE = 32;
constexpr int BB = 256;
constexpr int MAX_ELS = 65536;

constexpr int NCHUNK = 4;                 // column chunks; slice on 2 XCDs
constexpr int CHUNK_COLS = 64;            // fp8 bytes per row per chunk
constexpr size_t SLICE_BYTES = (size_t)MAX_ELS * CHUNK_COLS;  // 4 MB
constexpr int NPB = 64;                   // nodes per block (main kernel)

typedef float floatx2 __attribute__((ext_vector_type(2)));
typedef float f32x4 __attribute__((ext_vector_type(4)));
typedef unsigned int u32x4 __attribute__((ext_vector_type(4)));

__device__ inline int pack4_fp8(float4 v) {
    const int a = __hip_cvt_float_to_fp8(__expf(v.x), __HIP_SATFINITE, __HIP_E4M3);
    const int b = __hip_cvt_float_to_fp8(__expf(v.y), __HIP_SATFINITE, __HIP_E4M3);
    const int c = __hip_cvt_float_to_fp8(__expf(v.z), __HIP_SATFINITE, __HIP_E4M3);
    const int d = __hip_cvt_float_to_fp8(__expf(v.w), __HIP_SATFINITE, __HIP_E4M3);
    return a | (b << 8) | (c << 16) | (d << 24);
}

// ---- pre-pass 1: G[c][r][0..63] = fp8(exp(element_mars[r][c*64..c*64+63])) ----
// wave -> (16-row group, one chunk). lane l: r_local = l>>2, quarter q = l&3.
// read: em[r][c*64 + q*16 .. +16) = 64B contiguous per lane (coalesced).
// write: int4 at G + c*4MB + r*64 + q*16 -> per-wave 1KB contiguous.
__global__ __launch_bounds__(256)
void exp_convert_kernel(const float4* __restrict__ em, unsigned char* __restrict__ G)
{
    const int wid  = blockIdx.x * 4 + (threadIdx.x >> 6);
    const int lane = threadIdx.x & 63;
    const int c    = wid & 3;
    const int rg   = wid >> 2;                  // [0, 4096)
    const int r    = rg * 16 + (lane >> 2);
    const int q    = lane & 3;

    const float4* src = em + (size_t)r * 64 + c * 16 + q * 4;
    const float4 v0 = src[0], v1 = src[1], v2 = src[2], v3 = src[3];
    int4 o;
    o.x = pack4_fp8(v0);
    o.y = pack4_fp8(v1);
    o.z = pack4_fp8(v2);
    o.w = pack4_fp8(v3);
    *reinterpret_cast<int4*>(G + (size_t)c * SLICE_BYTES + (size_t)r * CHUNK_COLS
                               + q * 16) = o;
}

// ---- pre-pass 2: WC[i] = (cids[i] as u16) | (f16(params[pids[i]]) << 16) ----
__global__ __launch_bounds__(256)
void pack_wc_kernel(const float* __restrict__ params, const int* __restrict__ cids,
                    const int* __restrict__ pids, unsigned int* __restrict__ WC)
{
    const int i = blockIdx.x * 256 + threadIdx.x;
    const unsigned int cid = (unsigned int)cids[i] & 0xFFFFu;   // MAX_ELS = 2^16
    const float w = params[pids[i]];
    const unsigned int h = (unsigned int)__half_as_ushort(__float2half(w));
    WC[i] = cid | (h << 16);
}

// ---- main: 64 nodes/block x 64 cols; chunk = blockIdx%4 -> slice on 2 XCDs ----
// 16 nodes/wave, 4 lanes/node, dwordx4 (16B) per lane = ONE 64B request/(node,e).
__global__ __launch_bounds__(256)
void sum_main_kernel(const unsigned char* __restrict__ G, const unsigned int* __restrict__ WC,
                     const int* __restrict__ nids, float* __restrict__ out)
{
    const int chunk = blockIdx.x & (NCHUNK - 1);
    const int g     = blockIdx.x >> 2;          // node-group of 64
    const int tid   = threadIdx.x;

    // packed (cid,w); stride 33 -> e-indexed reads land on distinct banks.
    __shared__ unsigned int s_wc[NPB * 33];
    {
        const u32x4* WC4 = reinterpret_cast<const u32x4*>(WC);
        const u32x4 v0 = __builtin_nontemporal_load(WC4 + g * 512 + tid);
        const u32x4 v1 = __builtin_nontemporal_load(WC4 + g * 512 + 256 + tid);
        const int n0 = tid >> 3;
        const int e0 = (tid & 7) * 4;
        s_wc[n0 * 33 + e0 + 0] = v0.x;
        s_wc[n0 * 33 + e0 + 1] = v0.y;
        s_wc[n0 * 33 + e0 + 2] = v0.z;
        s_wc[n0 * 33 + e0 + 3] = v0.w;
        const int n1 = 32 + n0;
        s_wc[n1 * 33 + e0 + 0] = v1.x;
        s_wc[n1 * 33 + e0 + 1] = v1.y;
        s_wc[n1 * 33 + e0 + 2] = v1.z;
        s_wc[n1 * 33 + e0 + 3] = v1.w;
    }
    __syncthreads();

    const int wave = tid >> 6;
    const int lane = tid & 63;
    const int nl   = wave * 16 + (lane >> 2);   // node-local 0..63
    const int l4   = lane & 3;                  // 16 cols of the 64-col slice
    const unsigned char* Gs = G + (size_t)chunk * SLICE_BYTES + l4 * 16;
    const unsigned int* wcrow = s_wc + nl * 33;

    float acc[16];
#pragma unroll
    for (int k = 0; k < 16; ++k) acc[k] = 0.f;

#pragma unroll
    for (int e = 0; e < EE; ++e) {
        const unsigned int wc = wcrow[e];
        const u32x4 u = *reinterpret_cast<const u32x4*>(Gs + ((wc & 0xFFFFu) << 6));
        const float w = __half2float(__ushort_as_half((unsigned short)(wc >> 16)));
        const floatx2 p0 = __builtin_amdgcn_cvt_pk_f32_fp8(u.x, false);
        const floatx2 p1 = __builtin_amdgcn_cvt_pk_f32_fp8(u.x, true);
        const floatx2 p2 = __builtin_amdgcn_cvt_pk_f32_fp8(u.y, false);
        const floatx2 p3 = __builtin_amdgcn_cvt_pk_f32_fp8(u.y, true);
        const floatx2 p4 = __builtin_amdgcn_cvt_pk_f32_fp8(u.z, false);
        const floatx2 p5 = __builtin_amdgcn_cvt_pk_f32_fp8(u.z, true);
        const floatx2 p6 = __builtin_amdgcn_cvt_pk_f32_fp8(u.w, false);
        const floatx2 p7 = __builtin_amdgcn_cvt_pk_f32_fp8(u.w, true);
        acc[0]  = fmaf(p0.x, w, acc[0]);
        acc[1]  = fmaf(p0.y, w, acc[1]);
        acc[2]  = fmaf(p1.x, w, acc[2]);
        acc[3]  = fmaf(p1.y, w, acc[3]);
        acc[4]  = fmaf(p2.x, w, acc[4]);
        acc[5]  = fmaf(p2.y, w, acc[5]);
        acc[6]  = fmaf(p3.x, w, acc[6]);
        acc[7]  = fmaf(p3.y, w, acc[7]);
        acc[8]  = fmaf(p4.x, w, acc[8]);
        acc[9]  = fmaf(p4.y, w, acc[9]);
        acc[10] = fmaf(p5.x, w, acc[10]);
        acc[11] = fmaf(p5.y, w, acc[11]);
        acc[12] = fmaf(p6.x, w, acc[12]);
        acc[13] = fmaf(p6.y, w, acc[13]);
        acc[14] = fmaf(p7.x, w, acc[14]);
        acc[15] = fmaf(p7.y, w, acc[15]);
    }

    f32x4 r0, r1, r2, r3;
    r0.x = __logf(fmaxf(acc[0],  1e-10f));
    r0.y = __logf(fmaxf(acc[1],  1e-10f));
    r0.z = __logf(fmaxf(acc[2],  1e-10f));
    r0.w = __logf(fmaxf(acc[3],  1e-10f));
    r1.x = __logf(fmaxf(acc[4],  1e-10f));
    r1.y = __logf(fmaxf(acc[5],  1e-10f));
    r1.z = __logf(fmaxf(acc[6],  1e-10f));
    r1.w = __logf(fmaxf(acc[7],  1e-10f));
    r2.x = __logf(fmaxf(acc[8],  1e-10f));
    r2.y = __logf(fmaxf(acc[9],  1e-10f));
    r2.z = __logf(fmaxf(acc[10], 1e-10f));
    r2.w = __logf(fmaxf(acc[11], 1e-10f));
    r3.x = __logf(fmaxf(acc[12], 1e-10f));
    r3.y = __logf(fmaxf(acc[13], 1e-10f));
    r3.z = __logf(fmaxf(acc[14], 1e-10f));
    r3.w = __logf(fmaxf(acc[15], 1e-10f));

    const int n   = g * NPB + nl;
    const int row = nids[n];
    float* op = out + (size_t)row * BB + chunk * CHUNK_COLS + l4 * 16;
    __builtin_nontemporal_store(r0, reinterpret_cast<f32x4*>(op));
    __builtin_nontemporal_store(r1, reinterpret_cast<f32x4*>(op + 4));
    __builtin_nontemporal_store(r2, reinterpret_cast<f32x4*>(op + 8));
    __builtin_nontemporal_store(r3, reinterpret_cast<f32x4*>(op + 12));
}

// ---- fallback (ws too small): standalone fp32 version ----
__global__ __launch_bounds__(256, 2)
void sum_layer_fallback(const float* __restrict__ element_mars,
                        const float* __restrict__ params,
                        const int* __restrict__ nids,
                        const int* __restrict__ cids,
                        const int* __restrict__ pids,
                        float* __restrict__ out)
{
    const int tid  = threadIdx.x;
    const int wave = tid >> 6;
    const int lane = tid & 63;

    __shared__ int   s_cid[4][EE];
    __shared__ float s_w[4][EE];
    if (tid < 4 * EE) {
        const int wi = tid >> 5, e = tid & (EE - 1);
        const int gn = blockIdx.x * 4 + wi;
        s_cid[wi][e] = cids[gn * EE + e];
        s_w[wi][e]   = params[pids[gn * EE + e]];
    }
    __syncthreads();

    const int n = blockIdx.x * 4 + wave;
    float4 acc = make_float4(0.f, 0.f, 0.f, 0.f);
#pragma unroll
    for (int e = 0; e < EE; ++e) {
        const float4 v = *reinterpret_cast<const float4*>(
            element_mars + (size_t)s_cid[wave][e] * BB + 4 * lane);
        const float w = s_w[wave][e];
        acc.x = fmaf(__expf(v.x), w, acc.x);
        acc.y = fmaf(__expf(v.y), w, acc.y);
        acc.z = fmaf(__expf(v.z), w, acc.z);
        acc.w = fmaf(__expf(v.w), w, acc.w);
    }
    float4 r;
    r.x = __logf(fmaxf(acc.x, 1e-10f));
    r.y = __logf(fmaxf(acc.y, 1e-10f));
    r.z = __logf(fmaxf(acc.z, 1e-10f));
    r.w = __logf(fmaxf(acc.w, 1e-10f));
    *reinterpret_cast<float4*>(out + (size_t)nids[n] * BB + 4 * lane) = r;
}

extern "C" void kernel_launch(void* const* d_in, const int* in_sizes, int n_in,
                              void* d_out, int out_size, void* d_ws, size_t ws_size,
                              hipStream_t stream) {
    // inputs: node_mars[N,B], element_mars[MAX_ELS,B], params[N*E],
    //         nids[N], cids[N,E], pids[N,E]
    const float* element_mars = (const float*)d_in[1];
    const float* params       = (const float*)d_in[2];
    const int*   nids         = (const int*)d_in[3];
    const int*   cids         = (const int*)d_in[4];
    const int*   pids         = (const int*)d_in[5];
    float*       out          = (float*)d_out;

    const size_t g_bytes  = (size_t)NCHUNK * SLICE_BYTES;           // 16MB fp8
    const size_t wc_bytes = (size_t)NN * EE * sizeof(unsigned int); // 4MB

    if (ws_size >= g_bytes + wc_bytes) {
        unsigned char* G  = (unsigned char*)d_ws;
        unsigned int*  WC = (unsigned int*)((char*)d_ws + g_bytes);

        // 16384 waves: (65536/16 row-groups) x 4 chunks, 4 waves/block
        exp_convert_kernel<<<(MAX_ELS / 16) * NCHUNK / 4, 256, 0, stream>>>(
            (const float4*)element_mars, G);
        pack_wc_kernel<<<(NN * EE) / 256, 256, 0, stream>>>(params, cids, pids, WC);
        sum_main_kernel<<<(NN / NPB) * NCHUNK, 256, 0, stream>>>(G, WC, nids, out);
    } else {
        sum_layer_fallback<<<NN / 4, 256, 0, stream>>>(
            element_mars, params, nids, cids, pids, out);
    }
}